// Round 7
// baseline (90.600 us; speedup 1.0000x reference)
//
#include <hip/hip_runtime.h>
#include <hip/hip_fp16.h>

#define B_DIM   128
#define N_IN    16384
#define N_OUT   8192
#define N_EDGES (N_OUT * 64)

#define J_BLK    8                  // outputs (waves) per block
#define THREADS  (J_BLK * 64)       // 512
#define JGROUPS  (N_OUT / J_BLK)    // 1024

__device__ __forceinline__ int lower_bound_dev(const int* __restrict__ a, int n, int v) {
    int lo = 0, hi = n;
    while (lo < hi) {
        int mid = (lo + hi) >> 1;
        if (a[mid] < v) lo = mid + 1; else hi = mid;
    }
    return lo;
}

// One pass over edges: rowptr boundary-scatter + pack meta[e] = {src*rowbytes, w_bits}.
__global__ __launch_bounds__(256) void prep_kernel(const int* __restrict__ dst,
                                                   const int* __restrict__ src,
                                                   const float* __restrict__ w,
                                                   int* __restrict__ rp,
                                                   int2* __restrict__ meta) {
    const int e = blockIdx.x * 256 + threadIdx.x;
    if (e >= N_EDGES) return;
    const int d     = dst[e];
    const int dprev = (e == 0) ? -1 : dst[e - 1];
    for (int j = dprev + 1; j <= d; ++j) rp[j] = e;
    if (e == N_EDGES - 1)
        for (int j = d + 1; j <= N_OUT; ++j) rp[j] = N_EDGES;
    meta[e] = make_int2(src[e] * (B_DIM * 2), __float_as_int(w[e]));
}

// x[B][N_IN] (fp32) -> xTh[N_IN][B] (fp16). Read coalesced, write 128B half2 rows.
__global__ __launch_bounds__(256) void transpose_h_kernel(const float* __restrict__ x,
                                                          __half* __restrict__ xTh) {
    __shared__ float tile[64][33];      // [b_local][i_local]
    const int i0 = blockIdx.x * 32;
    const int b0 = blockIdx.y * 64;
    const int tx = threadIdx.x;         // 0..31
    const int ty = threadIdx.y;         // 0..7
#pragma unroll
    for (int r = 0; r < 64; r += 8)
        tile[ty + r][tx] = x[(size_t)(b0 + ty + r) * N_IN + (i0 + tx)];
    __syncthreads();
    __half2* out = (__half2*)xTh;
#pragma unroll
    for (int rr = 0; rr < 4; ++rr) {
        const int il = rr * 8 + ty;     // i_local 0..31
        const float a = tile[2 * tx][il];
        const float b = tile[2 * tx + 1][il];
        out[(size_t)(i0 + il) * (B_DIM / 2) + (b0 >> 1) + tx] = __floats2half2_rn(a, b);
    }
}

#define GATHER_FMA(K)                                                              \
    do {                                                                           \
        const int   idx = 4 * (K) + slot;                                          \
        const int   o   = __shfl(moff, idx, 64);                                   \
        const float wt  = __int_as_float(__shfl(mw, idx, 64));                     \
        const float4 raw = *(const float4*)(xb + (size_t)(unsigned)o);             \
        const __half2* hp = (const __half2*)&raw;                                  \
        _Pragma("unroll")                                                          \
        for (int q = 0; q < 4; ++q) {                                              \
            const float2 f = __half22float2(hp[q]);                                \
            acc[2 * q]     = fmaf(f.x, wt, acc[2 * q]);                            \
            acc[2 * q + 1] = fmaf(f.y, wt, acc[2 * q + 1]);                        \
        }                                                                          \
    } while (0)

// One WAVE per output j. Per 64-edge chunk: lane k prefetches meta of edge
// base+k (ONE coalesced 8B load for the whole chunk), then the inner loop
// distributes metas via __shfl (ds_bpermute, ~30cy) -- no global load on the
// critical path; all 16 gathers are independent -> deep MLP. Lane layout:
// slot=lane>>4 (edge within quad), bl=lane&15 (16B of the 256B fp16 row).
__global__ __launch_bounds__(THREADS, 4) void sparse_layer_h2(
        const __half* __restrict__ xTh, const float* __restrict__ bias,
        const int2* __restrict__ meta, const int* __restrict__ rp,
        float* __restrict__ y) {
    __shared__ float tile[J_BLK][132];

    const int tid  = threadIdx.x;
    const int wid  = tid >> 6;
    const int lane = tid & 63;
    const int slot = lane >> 4;         // 0..3
    const int bl   = lane & 15;
    const int j0   = blockIdx.x * J_BLK;
    const int j    = j0 + wid;

    const int e0 = __builtin_amdgcn_readfirstlane(rp[j]);
    const int e1 = __builtin_amdgcn_readfirstlane(rp[j + 1]);

    float acc[8] = {0.f, 0.f, 0.f, 0.f, 0.f, 0.f, 0.f, 0.f};
    const char* xb = (const char*)xTh + bl * 16;

    for (int base = e0; base < e1; base += 64) {
        const int n = min(64, e1 - base);
        int moff = 0, mw = 0;
        if (lane < n) {
            const int2 m = meta[base + lane];
            moff = m.x; mw = m.y;       // invalid lanes keep {0,0}: row 0, w=0
        }
        if (n == 64) {
#pragma unroll
            for (int k = 0; k < 16; ++k) GATHER_FMA(k);
        } else {
            for (int k = 0; 4 * k < n; ++k) GATHER_FMA(k);
        }
    }

    // Reduce over the 4 edge slots (lane bits 4..5).
#pragma unroll
    for (int m_ = 16; m_ <= 32; m_ <<= 1)
#pragma unroll
        for (int q = 0; q < 8; ++q) acc[q] += __shfl_xor(acc[q], m_, 64);

    if (slot == 0) {                    // lanes 0..15 hold b = 8*bl .. 8*bl+7
#pragma unroll
        for (int q = 0; q < 8; ++q) tile[wid][8 * bl + q] = acc[q];
    }
    __syncthreads();

    // Coalesced epilogue: 8 consecutive lanes -> 8 consecutive j (32B segments).
#pragma unroll
    for (int i = tid; i < B_DIM * J_BLK; i += THREADS) {
        const int bb = i >> 3;
        const int jj = i & (J_BLK - 1);
        const float v = tile[jj][bb] + bias[j0 + jj];
        y[(size_t)bb * N_OUT + (j0 + jj)] = fmaxf(v, 0.f);
    }
}

// Fallback (no usable workspace): per-output wave, fp32 gathers from row-major x.
__global__ __launch_bounds__(THREADS) void sparse_layer_fallback(
        const float* __restrict__ x, const float* __restrict__ w,
        const float* __restrict__ bias, const int* __restrict__ src,
        const int* __restrict__ dst, float* __restrict__ y) {
    __shared__ float tile[J_BLK][130];
    __shared__ int   srp[J_BLK + 1];

    const int tid  = threadIdx.x;
    const int wid  = tid >> 6;
    const int lane = tid & 63;
    const int j0   = blockIdx.x * J_BLK;

    if (tid <= J_BLK) srp[tid] = lower_bound_dev(dst, N_EDGES, j0 + tid);
    __syncthreads();

    const int e0 = srp[wid], e1 = srp[wid + 1];
    const int b0 = lane * 2;
    float acc0 = 0.f, acc1 = 0.f;
    for (int e = e0; e < e1; ++e) {
        const int   s  = src[e];
        const float wt = w[e];
        acc0 = fmaf(x[(size_t)b0 * N_IN + s], wt, acc0);
        acc1 = fmaf(x[(size_t)(b0 + 1) * N_IN + s], wt, acc1);
    }
    tile[wid][b0]     = acc0;
    tile[wid][b0 + 1] = acc1;
    __syncthreads();
#pragma unroll
    for (int i = tid; i < B_DIM * J_BLK; i += THREADS) {
        const int bb = i >> 3;
        const int jj = i & (J_BLK - 1);
        const float v = tile[jj][bb] + bias[j0 + jj];
        y[(size_t)bb * N_OUT + (j0 + jj)] = fmaxf(v, 0.f);
    }
}

extern "C" void kernel_launch(void* const* d_in, const int* in_sizes, int n_in,
                              void* d_out, int out_size, void* d_ws, size_t ws_size,
                              hipStream_t stream) {
    const float* x    = (const float*)d_in[0];
    const float* w    = (const float*)d_in[1];
    const float* bias = (const float*)d_in[2];
    const int*   esrc = (const int*)d_in[3];
    const int*   edst = (const int*)d_in[4];
    float*       y    = (float*)d_out;

    // ws layout: rp [0, 33KB) | meta [64KB, 64KB+4MB) | xTh [next, +4MB)
    const size_t META_OFF = 65536;
    const size_t META_BYTES = (size_t)N_EDGES * sizeof(int2);
    const size_t XT_OFF   = META_OFF + META_BYTES;
    const size_t XT_BYTES = (size_t)N_IN * B_DIM * sizeof(__half);

    const bool has_ws = ws_size >= XT_OFF + XT_BYTES;

    int*    rp   = (int*)d_ws;
    int2*   meta = (int2*)((char*)d_ws + META_OFF);
    __half* xTh  = (__half*)((char*)d_ws + XT_OFF);

    if (has_ws) {
        prep_kernel<<<dim3((N_EDGES + 255) / 256), 256, 0, stream>>>(edst, esrc, w, rp, meta);
        transpose_h_kernel<<<dim3(N_IN / 32, B_DIM / 64), dim3(32, 8), 0, stream>>>(x, xTh);
        sparse_layer_h2<<<dim3(JGROUPS), THREADS, 0, stream>>>(xTh, bias, meta, rp, y);
    } else {
        sparse_layer_fallback<<<dim3(N_OUT / J_BLK), THREADS, 0, stream>>>(x, w, bias, esrc, edst, y);
    }
}